// Round 14
// baseline (1178.008 us; speedup 1.0000x reference)
//
#include <hip/hip_runtime.h>
#include <hip/hip_bf16.h>
#include <math.h>

#define NQn 100000
#define NKVn 100000
#define NEn 2000000
// D=64, H=4, F=16
#define NB_TILE ((NQn + 63) / 64)

static __device__ __forceinline__ unsigned pack_bf2(float a, float b) {
    unsigned ua = __bfloat16_as_ushort(__float2bfloat16(a));
    unsigned ub = __bfloat16_as_ushort(__float2bfloat16(b));
    return ua | (ub << 16);
}

// ---------------- zero-init (accu bf16 rows + den f32) ---------------------
__global__ void zero_kernel(float4* __restrict__ p, int n4) {
    int i = blockIdx.x * blockDim.x + threadIdx.x;
    int stride = gridDim.x * blockDim.x;
    for (; i < n4; i += stride) p[i] = make_float4(0.f, 0.f, 0.f, 0.f);
}

// ---------------- q projection (tiled GEMM) -> packed bf16 qh --------------
// block: 64 rows x 64 cols, 256 threads, 4x4 per thread.
__global__ __launch_bounds__(256) void qproj_mm(const float* __restrict__ x,
                                                const float* __restrict__ W,
                                                unsigned* __restrict__ qh) {
    __shared__ float XT[64][68];   // [k][row], pad 68 keeps float4 alignment
    __shared__ float WS[64][64];   // [k][col]
    const int base = blockIdx.x * 64;
    for (int i = threadIdx.x; i < 4096; i += 256) WS[i >> 6][i & 63] = W[i];
    for (int i = threadIdx.x; i < 4096; i += 256) {
        int r = i >> 6, k = i & 63;
        int gr = min(base + r, NQn - 1);
        XT[k][r] = x[(size_t)gr * 64 + k];
    }
    __syncthreads();
    const int tc = threadIdx.x & 15, tr = threadIdx.x >> 4;
    float c[4][4] = {};
    #pragma unroll
    for (int k = 0; k < 64; ++k) {
        float4 a = *(const float4*)&XT[k][4 * tr];
        float4 w = *(const float4*)&WS[k][4 * tc];
        c[0][0] += a.x * w.x; c[0][1] += a.x * w.y; c[0][2] += a.x * w.z; c[0][3] += a.x * w.w;
        c[1][0] += a.y * w.x; c[1][1] += a.y * w.y; c[1][2] += a.y * w.z; c[1][3] += a.y * w.w;
        c[2][0] += a.z * w.x; c[2][1] += a.z * w.y; c[2][2] += a.z * w.z; c[2][3] += a.z * w.w;
        c[3][0] += a.w * w.x; c[3][1] += a.w * w.y; c[3][2] += a.w * w.z; c[3][3] += a.w * w.w;
    }
    #pragma unroll
    for (int i = 0; i < 4; ++i) {
        int r = base + 4 * tr + i;
        if (r < NQn) {
            qh[(size_t)r * 32 + 2 * tc]     = pack_bf2(c[i][0], c[i][1]);
            qh[(size_t)r * 32 + 2 * tc + 1] = pack_bf2(c[i][2], c[i][3]);
        }
    }
}

// ---------------- kv projection (tiled GEMM) -> packed bf16 kvh ------------
// block: 64 rows x 128 cols (k|v halves), 4x(4+4) per thread.
__global__ __launch_bounds__(256) void kvproj_mm(const float* __restrict__ x,
                                                 const float* __restrict__ W,
                                                 unsigned* __restrict__ kvh) {
    __shared__ float XT[64][68];
    __shared__ float WS[64][128];
    const int base = blockIdx.x * 64;
    for (int i = threadIdx.x; i < 8192; i += 256) WS[i >> 7][i & 127] = W[i];
    for (int i = threadIdx.x; i < 4096; i += 256) {
        int r = i >> 6, k = i & 63;
        int gr = min(base + r, NKVn - 1);
        XT[k][r] = x[(size_t)gr * 64 + k];
    }
    __syncthreads();
    const int tc = threadIdx.x & 15, tr = threadIdx.x >> 4;
    float ck[4][4] = {}, cv[4][4] = {};
    #pragma unroll
    for (int k = 0; k < 64; ++k) {
        float4 a  = *(const float4*)&XT[k][4 * tr];
        float4 w0 = *(const float4*)&WS[k][4 * tc];
        float4 w1 = *(const float4*)&WS[k][64 + 4 * tc];
        ck[0][0] += a.x * w0.x; ck[0][1] += a.x * w0.y; ck[0][2] += a.x * w0.z; ck[0][3] += a.x * w0.w;
        ck[1][0] += a.y * w0.x; ck[1][1] += a.y * w0.y; ck[1][2] += a.y * w0.z; ck[1][3] += a.y * w0.w;
        ck[2][0] += a.z * w0.x; ck[2][1] += a.z * w0.y; ck[2][2] += a.z * w0.z; ck[2][3] += a.z * w0.w;
        ck[3][0] += a.w * w0.x; ck[3][1] += a.w * w0.y; ck[3][2] += a.w * w0.z; ck[3][3] += a.w * w0.w;
        cv[0][0] += a.x * w1.x; cv[0][1] += a.x * w1.y; cv[0][2] += a.x * w1.z; cv[0][3] += a.x * w1.w;
        cv[1][0] += a.y * w1.x; cv[1][1] += a.y * w1.y; cv[1][2] += a.y * w1.z; cv[1][3] += a.y * w1.w;
        cv[2][0] += a.z * w1.x; cv[2][1] += a.z * w1.y; cv[2][2] += a.z * w1.z; cv[2][3] += a.z * w1.w;
        cv[3][0] += a.w * w1.x; cv[3][1] += a.w * w1.y; cv[3][2] += a.w * w1.z; cv[3][3] += a.w * w1.w;
    }
    #pragma unroll
    for (int i = 0; i < 4; ++i) {
        int r = base + 4 * tr + i;
        if (r < NKVn) {
            kvh[(size_t)r * 64 + 2 * tc]          = pack_bf2(ck[i][0], ck[i][1]);
            kvh[(size_t)r * 64 + 2 * tc + 1]      = pack_bf2(ck[i][2], ck[i][3]);
            kvh[(size_t)r * 64 + 32 + 2 * tc]     = pack_bf2(cv[i][0], cv[i][1]);
            kvh[(size_t)r * 64 + 32 + 2 * tc + 1] = pack_bf2(cv[i][2], cv[i][3]);
        }
    }
}

// ---------------- edge pass: bf16 gathers + pk_add_bf16 atomics ------------
// wave per edge. kvh row = 64 uints (k pairs 0-31, v pairs 32-63); qh row =
// 32 uints. Lanes 0-31: score pair `lane` (head = lane>>3). Lanes 32-63:
// v pair lane-32 -> one packed bf16x2 atomic into accu row (32 uints, 128B).
__global__ void edge_kernel(const int* __restrict__ t, const int* __restrict__ s,
                            const unsigned* __restrict__ qh,
                            const unsigned* __restrict__ kvh,
                            unsigned* __restrict__ accu, float* __restrict__ den) {
    const int lane = threadIdx.x & 63;
    const int wid  = blockIdx.x * (blockDim.x >> 6) + (threadIdx.x >> 6);
    const int nw   = gridDim.x * (blockDim.x >> 6);
    for (int e = wid; e < NEn; e += nw) {
        int ti = t[e], si = s[e];
        unsigned u  = kvh[(size_t)si * 64 + lane];
        unsigned qu = qh[(size_t)ti * 32 + (lane & 31)];
        float ea = __uint_as_float(u << 16);
        float eb = __uint_as_float(u & 0xffff0000u);
        float qa = __uint_as_float(qu << 16);
        float qb = __uint_as_float(qu & 0xffff0000u);
        float p = qa * ea + qb * eb;                    // valid in lanes 0-31
        p += __shfl_xor(p, 4, 64);
        p += __shfl_xor(p, 2, 64);
        p += __shfl_xor(p, 1, 64);
        float ex = __expf(p * 0.25f);                   // /sqrt(F), F=16
        float exv = __shfl(ex, lane & 31, 64);          // v-lane gets its head's ex
        if (lane >= 32) {
            unsigned pk = pack_bf2(exv * ea, exv * eb);
            unsigned* addr = accu + (size_t)ti * 32 + (lane - 32);
            asm volatile("global_atomic_pk_add_bf16 %0, %1, off"
                         :: "v"(addr), "v"(pk) : "memory");
        } else if ((lane & 7) == 0) {
            atomicAdd(&den[(size_t)ti * 4 + (lane >> 3)], ex);
        }
    }
}

// ---------------- epilogue (tiled GEMM): normalize + @ Wo + bo -------------
__global__ __launch_bounds__(256) void out_mm(const unsigned* __restrict__ accu,
                                              const float* __restrict__ den,
                                              const float* __restrict__ Wo,
                                              const float* __restrict__ bo,
                                              float* __restrict__ out) {
    __shared__ float XT[64][68];       // [dim][row] normalized values
    __shared__ float WS[64][64];
    __shared__ float DENS[256];        // [row][head]
    const int base = blockIdx.x * 64;
    for (int i = threadIdx.x; i < 4096; i += 256) WS[i >> 6][i & 63] = Wo[i];
    {
        int dr = threadIdx.x >> 2, h = threadIdx.x & 3;
        int gr = min(base + dr, NQn - 1);
        DENS[threadIdx.x] = den[(size_t)gr * 4 + h];
    }
    __syncthreads();
    for (int i = threadIdx.x; i < 2048; i += 256) {
        int r = i >> 5, j = i & 31;                     // row, pair
        int gr = min(base + r, NQn - 1);
        unsigned u = accu[(size_t)gr * 32 + j];
        float d = DENS[r * 4 + (j >> 3)];
        float va = __uint_as_float(u << 16);
        float vb = __uint_as_float(u & 0xffff0000u);
        XT[2 * j][r]     = (d > 0.f) ? va / d : 0.f;
        XT[2 * j + 1][r] = (d > 0.f) ? vb / d : 0.f;
    }
    __syncthreads();
    const int tc = threadIdx.x & 15, tr = threadIdx.x >> 4;
    float c[4][4] = {};
    #pragma unroll
    for (int k = 0; k < 64; ++k) {
        float4 a = *(const float4*)&XT[k][4 * tr];
        float4 w = *(const float4*)&WS[k][4 * tc];
        c[0][0] += a.x * w.x; c[0][1] += a.x * w.y; c[0][2] += a.x * w.z; c[0][3] += a.x * w.w;
        c[1][0] += a.y * w.x; c[1][1] += a.y * w.y; c[1][2] += a.y * w.z; c[1][3] += a.y * w.w;
        c[2][0] += a.z * w.x; c[2][1] += a.z * w.y; c[2][2] += a.z * w.z; c[2][3] += a.z * w.w;
        c[3][0] += a.w * w.x; c[3][1] += a.w * w.y; c[3][2] += a.w * w.z; c[3][3] += a.w * w.w;
    }
    float4 b4 = *(const float4*)&bo[4 * tc];
    #pragma unroll
    for (int i = 0; i < 4; ++i) {
        int r = base + 4 * tr + i;
        if (r < NQn) {
            float4 st = make_float4(c[i][0] + b4.x, c[i][1] + b4.y,
                                    c[i][2] + b4.z, c[i][3] + b4.w);
            *(float4*)&out[(size_t)r * 64 + 4 * tc] = st;
        }
    }
}

extern "C" void kernel_launch(void* const* d_in, const int* in_sizes, int n_in,
                              void* d_out, int out_size, void* d_ws, size_t ws_size,
                              hipStream_t stream) {
    const float* input = (const float*)d_in[0];
    const float* other = (const float*)d_in[1];
    const int*   t     = (const int*)  d_in[2];
    const int*   s     = (const int*)  d_in[3];
    const float* Wq    = (const float*)d_in[4];
    const float* Wkv   = (const float*)d_in[5];
    const float* Wo    = (const float*)d_in[6];
    const float* bo    = (const float*)d_in[7];
    float* out = (float*)d_out;

    // workspace layout
    char* w = (char*)d_ws;
    unsigned* qh   = (unsigned*)w;   w += (size_t)NQn * 32 * 4;    // 12.8 MB
    unsigned* kvh  = (unsigned*)w;   w += (size_t)NKVn * 64 * 4;   // 25.6 MB
    unsigned* accu = (unsigned*)w;   w += (size_t)NQn * 32 * 4;    // 12.8 MB (bf16 pairs)
    float*    den  = (float*)w;      w += (size_t)NQn * 4 * 4;     // 1.6 MB

    // zero the atomic accumulators (accu + den contiguous)
    int n4 = (NQn * 32 + NQn * 4) / 4;
    zero_kernel<<<2048, 256, 0, stream>>>((float4*)accu, n4);

    qproj_mm  <<<NB_TILE, 256, 0, stream>>>(input, Wq, qh);
    kvproj_mm <<<NB_TILE, 256, 0, stream>>>(other, Wkv, kvh);
    edge_kernel<<<4096, 256, 0, stream>>>(t, s, qh, kvh, accu, den);
    out_mm    <<<NB_TILE, 256, 0, stream>>>(accu, den, Wo, bo, out);
}